// Round 3
// baseline (329.621 us; speedup 1.0000x reference)
//
#include <hip/hip_runtime.h>
#include <math.h>

#define BB   2
#define NN   8192
#define SS   1024
#define KK   32
#define HID  256
#define NTH  256
#define PPT  32        // candidates per thread (NN/NTH)

typedef unsigned long long u64;
typedef unsigned int       u32;

// float4 component by constant index (folds under full unroll)
#define F4C(v, i) ((i)==0?(v).x:((i)==1?(v).y:((i)==2?(v).z:(v).w)))

__global__ __launch_bounds__(NTH, 5)
void snp_kernel(const float* __restrict__ pos,     // (B,N,3)
                const int*   __restrict__ snidx,   // (S,)
                const float* __restrict__ w_in,    // (3,HID)
                const float* __restrict__ b_in,    // (HID,)
                const float* __restrict__ w1,      // (HID,HID)
                const float* __restrict__ b1,      // (HID,)
                const float* __restrict__ w2,      // (HID,HID)
                const float* __restrict__ b2,      // (HID,)
                float*       __restrict__ out)     // (B,S,HID)
{
    const int bs   = blockIdx.x;        // 0 .. B*S-1
    const int b    = bs / SS;
    const int s    = bs - b * SS;
    const int t    = threadIdx.x;
    const int lane = t & 63;
    const int wv   = t >> 6;

    // 32 KB LDS -> 5 blocks/CU. KNN scratch inside h0 rows 28-31 (dead by the
    // time phase 4 writes those rows; ordering protected by barriers).
    __shared__ __align__(16) float h0[KK][HID];
    u64*   wl  = (u64*)&h0[28][0];      // 4 waves x 32 sorted keys (1 KB)
    int*   nbr = (int*)&h0[30][0];      // 32 int
    float* nbc = &h0[31][0];            // 96 f32

    const float* posb = pos + (size_t)b * (NN * 3);
    const int   sp = snidx[s];
    const float sx = posb[sp*3 + 0];
    const float sy = posb[sp*3 + 1];
    const float sz = posb[sp*3 + 2];

    // ---- Phase 1: distance bits (reference rounding exactly) ----
    u32 kd[PPT];
#pragma unroll
    for (int c = 0; c < PPT; ++c) {
        const int i = c * NTH + t;                 // coalesced across lanes
        const float dx = __fsub_rn(sx, posb[i*3 + 0]);
        const float dy = __fsub_rn(sy, posb[i*3 + 1]);
        const float dz = __fsub_rn(sz, posb[i*3 + 2]);
        const float sq = __fadd_rn(__fadd_rn(__fmul_rn(dx,dx), __fmul_rn(dy,dy)),
                                   __fmul_rn(dz,dz));
        kd[c] = __float_as_uint(__fsqrt_rn(sq));
    }

    // grouped minima: gm[q] = min over keys 8q..8q+7, packed (dist<<32)|idx
    u64 gm[4];
#pragma unroll
    for (int q = 0; q < 4; ++q) {
        u64 m = ((u64)kd[8*q] << 32) | (u32)((8*q) * NTH + t);
#pragma unroll
        for (int j = 1; j < 8; ++j) {
            const int c = 8*q + j;
            const u64 k2 = ((u64)kd[c] << 32) | (u32)(c * NTH + t);
            m = k2 < m ? k2 : m;
        }
        gm[q] = m;
    }

    // ---- Phase 2: wave-local 32 min-extractions, NO barriers ----
#pragma unroll 1
    for (int it = 0; it < KK; ++it) {
        const u64 g01  = gm[0] < gm[1] ? gm[0] : gm[1];
        const u64 g23  = gm[2] < gm[3] ? gm[2] : gm[3];
        const u64 lmin = g01 < g23 ? g01 : g23;
        u64 m = lmin;
#pragma unroll
        for (int off = 32; off > 0; off >>= 1) {
            const u64 o = __shfl_xor(m, off, 64);
            m = o < m ? o : m;
        }
        if (lane == 0) wl[wv*KK + it] = m;          // ascending per wave
        if (lmin == m) {                            // unique owner lane
#pragma unroll
            for (int q = 0; q < 4; ++q) {
                if (gm[q] == m) {
#pragma unroll
                    for (int j = 0; j < 8; ++j) {
                        const int c = 8*q + j;
                        const u64 k2 = ((u64)kd[c] << 32) | (u32)(c * NTH + t);
                        if (k2 == m) kd[c] = 0xFFFFFFFFu;   // +inf sentinel
                    }
                    u64 nm = ((u64)kd[8*q] << 32) | (u32)((8*q) * NTH + t);
#pragma unroll
                    for (int j = 1; j < 8; ++j) {
                        const int c = 8*q + j;
                        const u64 k2 = ((u64)kd[c] << 32) | (u32)(c * NTH + t);
                        nm = k2 < nm ? k2 : nm;
                    }
                    gm[q] = nm;
                }
            }
        }
    }
    __syncthreads();

    // ---- Phase 2b: wave 0 merges 4 sorted lists via bitonic merges ----
    if (t < 64) {
        auto bmerge = [&](u64 x) -> u64 {          // full-asc sort of bitonic seq
#pragma unroll
            for (int off = 32; off > 0; off >>= 1) {
                const u64 p  = __shfl_xor(x, off, 64);
                const u64 mn = x < p ? x : p;
                const u64 mx = x < p ? p : x;
                x = (lane & off) ? mx : mn;
            }
            return x;
        };
        u64 a = (lane < 32) ? wl[lane] : wl[32 + (63 - lane)];       // L0 asc + L1 desc
        a = bmerge(a);                                               // lanes0-31: top32(L0∪L1)
        u64 b2v = (lane < 32) ? wl[64 + lane] : wl[96 + (63 - lane)];// L2 asc + L3 desc
        b2v = bmerge(b2v);                                           // lanes0-31: top32(L2∪L3)
        const u64 sw = __shfl(b2v, 63 - lane, 64);                   // reverse M23
        u64 cf = (lane < 32) ? a : sw;
        cf = bmerge(cf);                                             // global top-32 asc
        if (lane < 32) nbr[lane] = (int)(u32)cf;                     // idx in low bits
    }
    __syncthreads();

    // ---- Phase 3: gather neighbor coords ----
    if (t < KK * 3) {
        nbc[t] = posb[(size_t)nbr[t / 3] * 3 + (t % 3)];
    }
    __syncthreads();

    // ---- Phase 4: h0 = coords @ w_in + b_in + sincos PE (thread = channel) ----
    {
        const int  c     = t;
        const int  dimi  = c / 84;                  // 84 = 2*42 channels per dim
        const int  cc    = c - dimi * 84;
        const bool hasPe = c < 252;
        const bool isCos = cc >= 42;
        const int  f     = isCos ? cc - 42 : cc;
        const float fcoef = (float)(-9.210340371976184 / 41.0);
        const float freqv = expf((float)f * fcoef);
        const int  di    = hasPe ? dimi : 0;

        const float wi0 = w_in[0*HID + c];
        const float wi1 = w_in[1*HID + c];
        const float wi2 = w_in[2*HID + c];
        const float bi  = b_in[c];

        auto h0val = [&](float x0, float x1, float x2) -> float {
            float v = fmaf(x2, wi2, fmaf(x1, wi1, fmaf(x0, wi0, bi)));
            if (hasPe) {
                const float xv  = (di == 0) ? x0 : ((di == 1) ? x1 : x2);
                const float ang = xv * freqv;
                v += isCos ? cosf(ang) : sinf(ang);
            }
            return v;
        };

        // rows 0..30: row 31 (nbc) untouched; rows 28-30 scratch is dead now
#pragma unroll 4
        for (int k = 0; k < KK - 1; ++k) {
            const float x0 = nbc[3*k+0], x1 = nbc[3*k+1], x2 = nbc[3*k+2];
            h0[k][c] = h0val(x0, x1, x2);
        }
        // k=31: its coords live where row 31 will be written -> stage via regs
        __syncthreads();
        const float x0 = nbc[93], x1 = nbc[94], x2 = nbc[95];
        __syncthreads();
        h0[KK-1][c] = h0val(x0, x1, x2);
    }
    __syncthreads();

    // ---- MLP: register-tiled. thread = 4 contiguous channels x 8 k-rows ----
    const int ct = t & 63;           // c-tile
    const int kt = t >> 6;           // k-group (wave-uniform)
    const int cb = ct * 4;
    const int kb = kt * 8;

    float acc[4][8];

    // ---- Phase 5: layer 1 (h0 @ w1 + b1) ----
    {
        const float4 bv = *(const float4*)&b1[cb];
#pragma unroll
        for (int ci = 0; ci < 4; ++ci)
#pragma unroll
            for (int kk = 0; kk < 8; ++kk) acc[ci][kk] = F4C(bv, ci);

        for (int j = 0; j < HID; j += 4) {
            float4 h[8];
#pragma unroll
            for (int kk = 0; kk < 8; ++kk)
                h[kk] = *(const float4*)&h0[kb + kk][j];    // broadcast b128
            float4 w[4];
#pragma unroll
            for (int jj = 0; jj < 4; ++jj)
                w[jj] = *(const float4*)&w1[(j + jj)*HID + cb];  // coalesced
#pragma unroll
            for (int jj = 0; jj < 4; ++jj)
#pragma unroll
                for (int ci = 0; ci < 4; ++ci) {
                    const float wvv = F4C(w[jj], ci);
#pragma unroll
                    for (int kk = 0; kk < 8; ++kk)
                        acc[ci][kk] = fmaf(F4C(h[kk], jj), wvv, acc[ci][kk]);
                }
        }
    }
    __syncthreads();                                 // all h0 reads done

    // gelu (tanh approx), write back into h0
    {
        const float kA = 0.7978845608028654f;        // sqrt(2/pi)
#pragma unroll
        for (int kk = 0; kk < 8; ++kk) {
            float4 g;
#pragma unroll
            for (int ci = 0; ci < 4; ++ci) {
                const float x  = acc[ci][kk];
                const float x3 = x * x * x;
                const float tv = tanhf(kA * fmaf(0.044715f, x3, x));
                const float gv = 0.5f * x * (1.0f + tv);
                if (ci == 0) g.x = gv; else if (ci == 1) g.y = gv;
                else if (ci == 2) g.z = gv; else g.w = gv;
            }
            *(float4*)&h0[kb + kk][cb] = g;
        }
    }
    __syncthreads();

    // ---- Phase 6: layer 2 (@ w2), partial over this thread's 8 k-rows ----
    {
#pragma unroll
        for (int ci = 0; ci < 4; ++ci)
#pragma unroll
            for (int kk = 0; kk < 8; ++kk) acc[ci][kk] = 0.0f;

        for (int j = 0; j < HID; j += 4) {
            float4 h[8];
#pragma unroll
            for (int kk = 0; kk < 8; ++kk)
                h[kk] = *(const float4*)&h0[kb + kk][j];
            float4 w[4];
#pragma unroll
            for (int jj = 0; jj < 4; ++jj)
                w[jj] = *(const float4*)&w2[(j + jj)*HID + cb];
#pragma unroll
            for (int jj = 0; jj < 4; ++jj)
#pragma unroll
                for (int ci = 0; ci < 4; ++ci) {
                    const float wvv = F4C(w[jj], ci);
#pragma unroll
                    for (int kk = 0; kk < 8; ++kk)
                        acc[ci][kk] = fmaf(F4C(h[kk], jj), wvv, acc[ci][kk]);
                }
        }
    }
    __syncthreads();                                 // h0 reads done; reuse as scratch

    // per-thread partial sums over its 8 k's
    {
        float4 part;
#pragma unroll
        for (int ci = 0; ci < 4; ++ci) {
            float p = acc[ci][0];
#pragma unroll
            for (int kk = 1; kk < 8; ++kk) p += acc[ci][kk];
            if (ci == 0) part.x = p; else if (ci == 1) part.y = p;
            else if (ci == 2) part.z = p; else part.w = p;
        }
        ((float4*)h0)[t] = part;                     // [kt][ct] -> flat t
    }
    __syncthreads();

    // cross-k-group reduce + bias + mean, wave 0 writes out
    if (t < 64) {
        const float4 p0 = ((const float4*)h0)[  0 + t];
        const float4 p1 = ((const float4*)h0)[ 64 + t];
        const float4 p2 = ((const float4*)h0)[128 + t];
        const float4 p3 = ((const float4*)h0)[192 + t];
        const float4 bv = *(const float4*)&b2[4 * t];
        float4 o;
        o.x = fmaf(((p0.x + p1.x) + p2.x) + p3.x, 1.0f / KK, bv.x);
        o.y = fmaf(((p0.y + p1.y) + p2.y) + p3.y, 1.0f / KK, bv.y);
        o.z = fmaf(((p0.z + p1.z) + p2.z) + p3.z, 1.0f / KK, bv.z);
        o.w = fmaf(((p0.w + p1.w) + p2.w) + p3.w, 1.0f / KK, bv.w);
        *(float4*)&out[(size_t)bs * HID + 4 * t] = o;
    }
}

extern "C" void kernel_launch(void* const* d_in, const int* in_sizes, int n_in,
                              void* d_out, int out_size, void* d_ws, size_t ws_size,
                              hipStream_t stream) {
    const float* pos  = (const float*)d_in[0];
    const int*   sni  = (const int*)  d_in[1];
    const float* w_in = (const float*)d_in[2];
    const float* b_in = (const float*)d_in[3];
    const float* w1   = (const float*)d_in[4];
    const float* b1   = (const float*)d_in[5];
    const float* w2   = (const float*)d_in[6];
    const float* b2   = (const float*)d_in[7];
    float* out = (float*)d_out;
    (void)d_ws; (void)ws_size; (void)in_sizes; (void)n_in; (void)out_size;

    dim3 grid(BB * SS), block(NTH);
    hipLaunchKernelGGL(snp_kernel, grid, block, 0, stream,
                       pos, sni, w_in, b_in, w1, b1, w2, b2, out);
}

// Round 4
// 266.878 us; speedup vs baseline: 1.2351x; 1.2351x over previous
//
#include <hip/hip_runtime.h>
#include <math.h>

#define BB   2
#define NN   8192
#define SS   1024
#define KK   32
#define HID  256
#define NTH  256
#define PPT  32        // candidates per thread (NN/NTH)
#define SENT 0xFFFFFFFFFFFFFFFFULL

typedef unsigned long long u64;
typedef unsigned int       u32;

// float4 component by constant index (folds under full unroll)
#define F4C(v, i) ((i)==0?(v).x:((i)==1?(v).y:((i)==2?(v).z:(v).w)))

// sorted-8 insertion: compare-swap carry chain (keeps s0..s7 ascending, drops max)
#define CSW(SI) { const u64 mn = x < (SI) ? x : (SI); const u64 mx = x < (SI) ? (SI) : x; (SI) = mn; x = mx; }
#define INS(KV) { u64 x = (KV); CSW(s0) CSW(s1) CSW(s2) CSW(s3) CSW(s4) CSW(s5) CSW(s6) CSW(s7) }

__global__ __launch_bounds__(NTH, 4)
void snp_kernel(const float* __restrict__ pos,     // (B,N,3)
                const int*   __restrict__ snidx,   // (S,)
                const float* __restrict__ w_in,    // (3,HID)
                const float* __restrict__ b_in,    // (HID,)
                const float* __restrict__ w1,      // (HID,HID)
                const float* __restrict__ b1,      // (HID,)
                const float* __restrict__ w2,      // (HID,HID)
                const float* __restrict__ b2,      // (HID,)
                float*       __restrict__ out)     // (B,S,HID)
{
    const int bs   = blockIdx.x;        // 0 .. B*S-1
    const int b    = bs / SS;
    const int s    = bs - b * SS;
    const int t    = threadIdx.x;
    const int lane = t & 63;
    const int wv   = t >> 6;

    // 32 KB LDS -> fits 4 blocks/CU alongside (256,4) reg budget.
    // KNN scratch inside h0 rows 28-31 (dead before phase 4 writes them).
    __shared__ __align__(16) float h0[KK][HID];
    u64*   wl  = (u64*)&h0[28][0];      // 4 waves x 32 sorted keys (1 KB, rows 28-29)
    int*   nbr = (int*)&h0[30][0];      // 32 int
    float* nbc = &h0[31][0];            // 96 f32

    const float* posb = pos + (size_t)b * (NN * 3);
    const int   sp = snidx[s];
    const float sx = posb[sp*3 + 0];
    const float sy = posb[sp*3 + 1];
    const float sz = posb[sp*3 + 2];

    // ---- Phase 1: stream distances (reference rounding), per-lane sorted top-8 ----
    u64 s0=SENT,s1=SENT,s2=SENT,s3=SENT,s4=SENT,s5=SENT,s6=SENT,s7=SENT;
#pragma unroll 4
    for (int c = 0; c < PPT; ++c) {
        const int i = c * NTH + t;                 // coalesced across lanes
        const float dx = __fsub_rn(sx, posb[i*3 + 0]);
        const float dy = __fsub_rn(sy, posb[i*3 + 1]);
        const float dz = __fsub_rn(sz, posb[i*3 + 2]);
        const float sq = __fadd_rn(__fadd_rn(__fmul_rn(dx,dx), __fmul_rn(dy,dy)),
                                   __fmul_rn(dz,dz));
        const u64 kv = ((u64)__float_as_uint(__fsqrt_rn(sq)) << 32) | (u32)i;
        INS(kv);
    }
    int nv = 8;

    // ---- Phase 2: wave-local 32 min-extractions, NO barriers ----
#pragma unroll 1
    for (int it = 0; it < KK; ++it) {
        u64 m = s0;                                 // offer own current min
#pragma unroll
        for (int off = 32; off > 0; off >>= 1) {
            const u64 o = __shfl_xor(m, off, 64);
            m = o < m ? o : m;
        }
        if (lane == 0) wl[wv*KK + it] = m;          // ascending per wave
        if (s0 == m) {                              // unique owner (idx in key)
            s0=s1; s1=s2; s2=s3; s3=s4; s4=s5; s5=s6; s6=s7; s7=SENT;
            if (--nv == 0) {                        // cold: lane owned 8 of wave top-32
                const u64 last = m;
                s0=s1=s2=s3=s4=s5=s6=s7=SENT;
#pragma unroll 4
                for (int c = 0; c < PPT; ++c) {
                    const int i = c * NTH + t;
                    const float dx = __fsub_rn(sx, posb[i*3 + 0]);
                    const float dy = __fsub_rn(sy, posb[i*3 + 1]);
                    const float dz = __fsub_rn(sz, posb[i*3 + 2]);
                    const float sq = __fadd_rn(__fadd_rn(__fmul_rn(dx,dx), __fmul_rn(dy,dy)),
                                               __fmul_rn(dz,dz));
                    u64 kv = ((u64)__float_as_uint(__fsqrt_rn(sq)) << 32) | (u32)i;
                    kv = kv > last ? kv : SENT;     // only keys after lastPopped
                    INS(kv);
                }
                nv = (int)(s0!=SENT)+(int)(s1!=SENT)+(int)(s2!=SENT)+(int)(s3!=SENT)
                   + (int)(s4!=SENT)+(int)(s5!=SENT)+(int)(s6!=SENT)+(int)(s7!=SENT);
            }
        }
    }
    __syncthreads();

    // ---- Phase 2b: wave 0 merges 4 sorted lists via bitonic merges ----
    if (t < 64) {
        auto bmerge = [&](u64 x) -> u64 {          // full-asc sort of bitonic seq
#pragma unroll
            for (int off = 32; off > 0; off >>= 1) {
                const u64 p  = __shfl_xor(x, off, 64);
                const u64 mn = x < p ? x : p;
                const u64 mx = x < p ? p : x;
                x = (lane & off) ? mx : mn;
            }
            return x;
        };
        u64 a = (lane < 32) ? wl[lane] : wl[32 + (63 - lane)];       // L0 asc + L1 desc
        a = bmerge(a);                                               // lanes0-31: top32(L0∪L1)
        u64 b2v = (lane < 32) ? wl[64 + lane] : wl[96 + (63 - lane)];// L2 asc + L3 desc
        b2v = bmerge(b2v);                                           // lanes0-31: top32(L2∪L3)
        const u64 sw = __shfl(b2v, 63 - lane, 64);                   // reverse M23
        u64 cf = (lane < 32) ? a : sw;
        cf = bmerge(cf);                                             // global top-32 asc
        if (lane < 32) nbr[lane] = (int)(u32)cf;                     // idx in low bits
    }
    __syncthreads();

    // ---- Phase 3: gather neighbor coords ----
    if (t < KK * 3) {
        nbc[t] = posb[(size_t)nbr[t / 3] * 3 + (t % 3)];
    }
    __syncthreads();

    // ---- Phase 4: h0 = coords @ w_in + b_in + sincos PE (thread = channel) ----
    {
        const int  c     = t;
        const int  dimi  = c / 84;                  // 84 = 2*42 channels per dim
        const int  cc    = c - dimi * 84;
        const bool hasPe = c < 252;
        const bool isCos = cc >= 42;
        const int  f     = isCos ? cc - 42 : cc;
        const float fcoef = (float)(-9.210340371976184 / 41.0);
        const float freqv = expf((float)f * fcoef);
        const int  di    = hasPe ? dimi : 0;

        const float wi0 = w_in[0*HID + c];
        const float wi1 = w_in[1*HID + c];
        const float wi2 = w_in[2*HID + c];
        const float bi  = b_in[c];

        auto h0val = [&](float x0, float x1, float x2) -> float {
            float v = fmaf(x2, wi2, fmaf(x1, wi1, fmaf(x0, wi0, bi)));
            if (hasPe) {
                const float xv  = (di == 0) ? x0 : ((di == 1) ? x1 : x2);
                const float ang = xv * freqv;
                v += isCos ? cosf(ang) : sinf(ang);
            }
            return v;
        };

        // rows 0..30: row 31 (nbc) untouched; rows 28-30 scratch is dead now
#pragma unroll 4
        for (int k = 0; k < KK - 1; ++k) {
            const float x0 = nbc[3*k+0], x1 = nbc[3*k+1], x2 = nbc[3*k+2];
            h0[k][c] = h0val(x0, x1, x2);
        }
        // k=31: its coords live where row 31 will be written -> stage via regs
        __syncthreads();
        const float x0 = nbc[93], x1 = nbc[94], x2 = nbc[95];
        __syncthreads();
        h0[KK-1][c] = h0val(x0, x1, x2);
    }
    __syncthreads();

    // ---- MLP: register-tiled. thread = 4 contiguous channels x 8 k-rows ----
    const int ct = t & 63;           // c-tile
    const int kt = t >> 6;           // k-group (wave-uniform)
    const int cb = ct * 4;
    const int kb = kt * 8;

    float acc[4][8];

    // ---- Phase 5: layer 1 (h0 @ w1 + b1) ----
    {
        const float4 bv = *(const float4*)&b1[cb];
#pragma unroll
        for (int ci = 0; ci < 4; ++ci)
#pragma unroll
            for (int kk = 0; kk < 8; ++kk) acc[ci][kk] = F4C(bv, ci);

        for (int j = 0; j < HID; j += 4) {
            float4 h[8];
#pragma unroll
            for (int kk = 0; kk < 8; ++kk)
                h[kk] = *(const float4*)&h0[kb + kk][j];    // broadcast b128
            float4 w[4];
#pragma unroll
            for (int jj = 0; jj < 4; ++jj)
                w[jj] = *(const float4*)&w1[(j + jj)*HID + cb];  // coalesced
#pragma unroll
            for (int jj = 0; jj < 4; ++jj)
#pragma unroll
                for (int ci = 0; ci < 4; ++ci) {
                    const float wvv = F4C(w[jj], ci);
#pragma unroll
                    for (int kk = 0; kk < 8; ++kk)
                        acc[ci][kk] = fmaf(F4C(h[kk], jj), wvv, acc[ci][kk]);
                }
        }
    }
    __syncthreads();                                 // all h0 reads done

    // gelu (tanh approx), write back into h0
    {
        const float kA = 0.7978845608028654f;        // sqrt(2/pi)
#pragma unroll
        for (int kk = 0; kk < 8; ++kk) {
            float4 g;
#pragma unroll
            for (int ci = 0; ci < 4; ++ci) {
                const float x  = acc[ci][kk];
                const float x3 = x * x * x;
                const float tv = tanhf(kA * fmaf(0.044715f, x3, x));
                const float gv = 0.5f * x * (1.0f + tv);
                if (ci == 0) g.x = gv; else if (ci == 1) g.y = gv;
                else if (ci == 2) g.z = gv; else g.w = gv;
            }
            *(float4*)&h0[kb + kk][cb] = g;
        }
    }
    __syncthreads();

    // ---- Phase 6: layer 2 (@ w2), partial over this thread's 8 k-rows ----
    {
#pragma unroll
        for (int ci = 0; ci < 4; ++ci)
#pragma unroll
            for (int kk = 0; kk < 8; ++kk) acc[ci][kk] = 0.0f;

        for (int j = 0; j < HID; j += 4) {
            float4 h[8];
#pragma unroll
            for (int kk = 0; kk < 8; ++kk)
                h[kk] = *(const float4*)&h0[kb + kk][j];
            float4 w[4];
#pragma unroll
            for (int jj = 0; jj < 4; ++jj)
                w[jj] = *(const float4*)&w2[(j + jj)*HID + cb];
#pragma unroll
            for (int jj = 0; jj < 4; ++jj)
#pragma unroll
                for (int ci = 0; ci < 4; ++ci) {
                    const float wvv = F4C(w[jj], ci);
#pragma unroll
                    for (int kk = 0; kk < 8; ++kk)
                        acc[ci][kk] = fmaf(F4C(h[kk], jj), wvv, acc[ci][kk]);
                }
        }
    }
    __syncthreads();                                 // h0 reads done; reuse as scratch

    // per-thread partial sums over its 8 k's
    {
        float4 part;
#pragma unroll
        for (int ci = 0; ci < 4; ++ci) {
            float p = acc[ci][0];
#pragma unroll
            for (int kk = 1; kk < 8; ++kk) p += acc[ci][kk];
            if (ci == 0) part.x = p; else if (ci == 1) part.y = p;
            else if (ci == 2) part.z = p; else part.w = p;
        }
        ((float4*)h0)[t] = part;                     // [kt][ct] -> flat t
    }
    __syncthreads();

    // cross-k-group reduce + bias + mean, wave 0 writes out
    if (t < 64) {
        const float4 p0 = ((const float4*)h0)[  0 + t];
        const float4 p1 = ((const float4*)h0)[ 64 + t];
        const float4 p2 = ((const float4*)h0)[128 + t];
        const float4 p3 = ((const float4*)h0)[192 + t];
        const float4 bv = *(const float4*)&b2[4 * t];
        float4 o;
        o.x = fmaf(((p0.x + p1.x) + p2.x) + p3.x, 1.0f / KK, bv.x);
        o.y = fmaf(((p0.y + p1.y) + p2.y) + p3.y, 1.0f / KK, bv.y);
        o.z = fmaf(((p0.z + p1.z) + p2.z) + p3.z, 1.0f / KK, bv.z);
        o.w = fmaf(((p0.w + p1.w) + p2.w) + p3.w, 1.0f / KK, bv.w);
        *(float4*)&out[(size_t)bs * HID + 4 * t] = o;
    }
}

extern "C" void kernel_launch(void* const* d_in, const int* in_sizes, int n_in,
                              void* d_out, int out_size, void* d_ws, size_t ws_size,
                              hipStream_t stream) {
    const float* pos  = (const float*)d_in[0];
    const int*   sni  = (const int*)  d_in[1];
    const float* w_in = (const float*)d_in[2];
    const float* b_in = (const float*)d_in[3];
    const float* w1   = (const float*)d_in[4];
    const float* b1   = (const float*)d_in[5];
    const float* w2   = (const float*)d_in[6];
    const float* b2   = (const float*)d_in[7];
    float* out = (float*)d_out;
    (void)d_ws; (void)ws_size; (void)in_sizes; (void)n_in; (void)out_size;

    dim3 grid(BB * SS), block(NTH);
    hipLaunchKernelGGL(snp_kernel, grid, block, 0, stream,
                       pos, sni, w_in, b_in, w1, b1, w2, b2, out);
}

// Round 5
// 245.765 us; speedup vs baseline: 1.3412x; 1.0859x over previous
//
#include <hip/hip_runtime.h>
#include <math.h>

#define BB   2
#define NN   8192
#define SS   1024
#define KK   32
#define HID  256
#define NTH  256
#define PPT  32        // candidates per thread (NN/NTH)
#define SENT 0xFFFFFFFFFFFFFFFFULL

typedef unsigned long long u64;
typedef unsigned int       u32;
typedef float v2f __attribute__((ext_vector_type(2)));

// float4 component by constant index (folds under full unroll)
#define F4C(v, i) ((i)==0?(v).x:((i)==1?(v).y:((i)==2?(v).z:(v).w)))

// sorted-8 insertion: compare-swap carry chain (keeps s0..s7 ascending, drops max)
#define CSW(SI) { const u64 mn = x < (SI) ? x : (SI); const u64 mx = x < (SI) ? (SI) : x; (SI) = mn; x = mx; }
#define INS(KV) { u64 x = (KV); CSW(s0) CSW(s1) CSW(s2) CSW(s3) CSW(s4) CSW(s5) CSW(s6) CSW(s7) }

// tanh via hardware exp/rcp: tanh(y) = 1 - 2/(1+e^{2y}); saturates correctly.
__device__ __forceinline__ float tanh_fast(float y) {
    const float e = __expf(2.0f * y);
    const float r = __builtin_amdgcn_rcpf(e + 1.0f);
    return fmaf(-2.0f, r, 1.0f);
}

__global__ __launch_bounds__(NTH, 4)
void snp_kernel(const float* __restrict__ pos,     // (B,N,3)
                const int*   __restrict__ snidx,   // (S,)
                const float* __restrict__ w_in,    // (3,HID)
                const float* __restrict__ b_in,    // (HID,)
                const float* __restrict__ w1,      // (HID,HID)
                const float* __restrict__ b1,      // (HID,)
                const float* __restrict__ w2,      // (HID,HID)
                const float* __restrict__ b2,      // (HID,)
                float*       __restrict__ out)     // (B,S,HID)
{
    const int bs   = blockIdx.x;        // 0 .. B*S-1
    const int b    = bs / SS;
    const int s    = bs - b * SS;
    const int t    = threadIdx.x;
    const int lane = t & 63;
    const int wv   = t >> 6;

    // 32 KB LDS. KNN scratch inside h0 rows 28-31 (dead before phase 4 writes).
    __shared__ __align__(16) float h0[KK][HID];
    u64*   wl  = (u64*)&h0[28][0];      // 4 waves x 32 sorted keys (1 KB, rows 28-29)
    int*   nbr = (int*)&h0[30][0];      // 32 int
    float* nbc = &h0[31][0];            // 96 f32

    const float* posb = pos + (size_t)b * (NN * 3);
    const int   sp = snidx[s];
    const float sx = posb[sp*3 + 0];
    const float sy = posb[sp*3 + 1];
    const float sz = posb[sp*3 + 2];

    // ---- Phase 1: stream distances (reference rounding), per-lane sorted top-8 ----
    u64 s0=SENT,s1=SENT,s2=SENT,s3=SENT,s4=SENT,s5=SENT,s6=SENT,s7=SENT;
#pragma unroll 4
    for (int c = 0; c < PPT; ++c) {
        const int i = c * NTH + t;                 // coalesced across lanes
        const float dx = __fsub_rn(sx, posb[i*3 + 0]);
        const float dy = __fsub_rn(sy, posb[i*3 + 1]);
        const float dz = __fsub_rn(sz, posb[i*3 + 2]);
        const float sq = __fadd_rn(__fadd_rn(__fmul_rn(dx,dx), __fmul_rn(dy,dy)),
                                   __fmul_rn(dz,dz));
        const u64 kv = ((u64)__float_as_uint(__fsqrt_rn(sq)) << 32) | (u32)i;
        INS(kv);
    }
    int nv = 8;

    // ---- Phase 2: wave-local 32 min-extractions, NO barriers ----
#pragma unroll 1
    for (int it = 0; it < KK; ++it) {
        u64 m = s0;                                 // offer own current min
#pragma unroll
        for (int off = 32; off > 0; off >>= 1) {
            const u64 o = __shfl_xor(m, off, 64);
            m = o < m ? o : m;
        }
        if (lane == 0) wl[wv*KK + it] = m;          // ascending per wave
        if (s0 == m) {                              // unique owner (idx in key)
            s0=s1; s1=s2; s2=s3; s3=s4; s4=s5; s5=s6; s6=s7; s7=SENT;
            if (--nv == 0) {                        // cold: lane owned 8 of wave top-32
                const u64 last = m;
                s0=s1=s2=s3=s4=s5=s6=s7=SENT;
#pragma unroll 4
                for (int c = 0; c < PPT; ++c) {
                    const int i = c * NTH + t;
                    const float dx = __fsub_rn(sx, posb[i*3 + 0]);
                    const float dy = __fsub_rn(sy, posb[i*3 + 1]);
                    const float dz = __fsub_rn(sz, posb[i*3 + 2]);
                    const float sq = __fadd_rn(__fadd_rn(__fmul_rn(dx,dx), __fmul_rn(dy,dy)),
                                               __fmul_rn(dz,dz));
                    u64 kv = ((u64)__float_as_uint(__fsqrt_rn(sq)) << 32) | (u32)i;
                    kv = kv > last ? kv : SENT;     // only keys after lastPopped
                    INS(kv);
                }
                nv = (int)(s0!=SENT)+(int)(s1!=SENT)+(int)(s2!=SENT)+(int)(s3!=SENT)
                   + (int)(s4!=SENT)+(int)(s5!=SENT)+(int)(s6!=SENT)+(int)(s7!=SENT);
            }
        }
    }
    __syncthreads();

    // ---- Phase 2b: wave 0 merges 4 sorted lists via bitonic merges ----
    if (t < 64) {
        auto bmerge = [&](u64 x) -> u64 {          // full-asc sort of bitonic seq
#pragma unroll
            for (int off = 32; off > 0; off >>= 1) {
                const u64 p  = __shfl_xor(x, off, 64);
                const u64 mn = x < p ? x : p;
                const u64 mx = x < p ? p : x;
                x = (lane & off) ? mx : mn;
            }
            return x;
        };
        u64 a = (lane < 32) ? wl[lane] : wl[32 + (63 - lane)];       // L0 asc + L1 desc
        a = bmerge(a);                                               // lanes0-31: top32(L0∪L1)
        u64 b2v = (lane < 32) ? wl[64 + lane] : wl[96 + (63 - lane)];// L2 asc + L3 desc
        b2v = bmerge(b2v);                                           // lanes0-31: top32(L2∪L3)
        const u64 sw = __shfl(b2v, 63 - lane, 64);                   // reverse M23
        u64 cf = (lane < 32) ? a : sw;
        cf = bmerge(cf);                                             // global top-32 asc
        if (lane < 32) nbr[lane] = (int)(u32)cf;                     // idx in low bits
    }
    __syncthreads();

    // ---- Phase 3: gather neighbor coords ----
    if (t < KK * 3) {
        nbc[t] = posb[(size_t)nbr[t / 3] * 3 + (t % 3)];
    }
    __syncthreads();

    // ---- Phase 4: h0 = coords @ w_in + b_in + sincos PE (thread = channel) ----
    {
        const int  c     = t;
        const int  dimi  = c / 84;                  // 84 = 2*42 channels per dim
        const int  cc    = c - dimi * 84;
        const bool hasPe = c < 252;
        const bool isCos = cc >= 42;
        const int  f     = isCos ? cc - 42 : cc;
        const float fcoef = (float)(-9.210340371976184 / 41.0);
        const float freqv = expf((float)f * fcoef);
        const int  di    = hasPe ? dimi : 0;

        const float wi0 = w_in[0*HID + c];
        const float wi1 = w_in[1*HID + c];
        const float wi2 = w_in[2*HID + c];
        const float bi  = b_in[c];

        auto h0val = [&](float x0, float x1, float x2) -> float {
            float v = fmaf(x2, wi2, fmaf(x1, wi1, fmaf(x0, wi0, bi)));
            if (hasPe) {
                const float xv  = (di == 0) ? x0 : ((di == 1) ? x1 : x2);
                const float ang = xv * freqv;
                v += isCos ? __cosf(ang) : __sinf(ang);   // native (args |x|<~6)
            }
            return v;
        };

        // rows 0..30: row 31 (nbc) untouched; rows 28-30 scratch is dead now
#pragma unroll 4
        for (int k = 0; k < KK - 1; ++k) {
            const float x0 = nbc[3*k+0], x1 = nbc[3*k+1], x2 = nbc[3*k+2];
            h0[k][c] = h0val(x0, x1, x2);
        }
        // k=31: its coords live where row 31 will be written -> stage via regs
        __syncthreads();
        const float x0 = nbc[93], x1 = nbc[94], x2 = nbc[95];
        __syncthreads();
        h0[KK-1][c] = h0val(x0, x1, x2);
    }
    __syncthreads();

    // ---- MLP: register-tiled, packed-fp32 FMA pairs along ci ----
    // acc[ci][kk]: ci 0,1 -> a01[kk].{x,y}; ci 2,3 -> a23[kk].{x,y}.
    // Per-element op and accumulation order identical to scalar version.
    const int ct = t & 63;           // c-tile
    const int kt = t >> 6;           // k-group (wave-uniform)
    const int cb = ct * 4;
    const int kb = kt * 8;

    v2f a01[8], a23[8];

    // ---- Phase 5: layer 1 (h0 @ w1 + b1) ----
    {
        const float4 bv = *(const float4*)&b1[cb];
        const v2f blo = {bv.x, bv.y};
        const v2f bhi = {bv.z, bv.w};
#pragma unroll
        for (int kk = 0; kk < 8; ++kk) { a01[kk] = blo; a23[kk] = bhi; }

        for (int j = 0; j < HID; j += 4) {
            float4 h[8];
#pragma unroll
            for (int kk = 0; kk < 8; ++kk)
                h[kk] = *(const float4*)&h0[kb + kk][j];    // broadcast b128
            float4 w[4];
#pragma unroll
            for (int jj = 0; jj < 4; ++jj)
                w[jj] = *(const float4*)&w1[(j + jj)*HID + cb];  // coalesced
#pragma unroll
            for (int jj = 0; jj < 4; ++jj) {
                const v2f wlo = {F4C(w[jj],0), F4C(w[jj],1)};    // consecutive VGPRs
                const v2f whi = {F4C(w[jj],2), F4C(w[jj],3)};
#pragma unroll
                for (int kk = 0; kk < 8; ++kk) {
                    const float hv = F4C(h[kk], jj);
                    const v2f hs = {hv, hv};                      // splat (op_sel-foldable)
                    a01[kk] = __builtin_elementwise_fma(hs, wlo, a01[kk]);
                    a23[kk] = __builtin_elementwise_fma(hs, whi, a23[kk]);
                }
            }
        }
    }
    __syncthreads();                                 // all h0 reads done

    // gelu (tanh approx), write back into h0
    {
        const float kA = 0.7978845608028654f;        // sqrt(2/pi)
#pragma unroll
        for (int kk = 0; kk < 8; ++kk) {
            float4 g;
#pragma unroll
            for (int ci = 0; ci < 4; ++ci) {
                const float x  = (ci==0) ? a01[kk].x : (ci==1) ? a01[kk].y
                               : (ci==2) ? a23[kk].x : a23[kk].y;
                const float x3 = x * x * x;
                const float tv = tanh_fast(kA * fmaf(0.044715f, x3, x));
                const float gv = 0.5f * x * (1.0f + tv);
                if (ci == 0) g.x = gv; else if (ci == 1) g.y = gv;
                else if (ci == 2) g.z = gv; else g.w = gv;
            }
            *(float4*)&h0[kb + kk][cb] = g;
        }
    }
    __syncthreads();

    // ---- Phase 6: layer 2 (@ w2), partial over this thread's 8 k-rows ----
    {
        const v2f z = {0.0f, 0.0f};
#pragma unroll
        for (int kk = 0; kk < 8; ++kk) { a01[kk] = z; a23[kk] = z; }

        for (int j = 0; j < HID; j += 4) {
            float4 h[8];
#pragma unroll
            for (int kk = 0; kk < 8; ++kk)
                h[kk] = *(const float4*)&h0[kb + kk][j];
            float4 w[4];
#pragma unroll
            for (int jj = 0; jj < 4; ++jj)
                w[jj] = *(const float4*)&w2[(j + jj)*HID + cb];
#pragma unroll
            for (int jj = 0; jj < 4; ++jj) {
                const v2f wlo = {F4C(w[jj],0), F4C(w[jj],1)};
                const v2f whi = {F4C(w[jj],2), F4C(w[jj],3)};
#pragma unroll
                for (int kk = 0; kk < 8; ++kk) {
                    const float hv = F4C(h[kk], jj);
                    const v2f hs = {hv, hv};
                    a01[kk] = __builtin_elementwise_fma(hs, wlo, a01[kk]);
                    a23[kk] = __builtin_elementwise_fma(hs, whi, a23[kk]);
                }
            }
        }
    }
    __syncthreads();                                 // h0 reads done; reuse as scratch

    // per-thread partial sums over its 8 k's (k ascending, per ci)
    {
        float4 part;
#pragma unroll
        for (int ci = 0; ci < 4; ++ci) {
            float p = (ci==0) ? a01[0].x : (ci==1) ? a01[0].y
                    : (ci==2) ? a23[0].x : a23[0].y;
#pragma unroll
            for (int kk = 1; kk < 8; ++kk) {
                const float v = (ci==0) ? a01[kk].x : (ci==1) ? a01[kk].y
                              : (ci==2) ? a23[kk].x : a23[kk].y;
                p += v;
            }
            if (ci == 0) part.x = p; else if (ci == 1) part.y = p;
            else if (ci == 2) part.z = p; else part.w = p;
        }
        ((float4*)h0)[t] = part;                     // [kt][ct] -> flat t
    }
    __syncthreads();

    // cross-k-group reduce + bias + mean, wave 0 writes out
    if (t < 64) {
        const float4 p0 = ((const float4*)h0)[  0 + t];
        const float4 p1 = ((const float4*)h0)[ 64 + t];
        const float4 p2 = ((const float4*)h0)[128 + t];
        const float4 p3 = ((const float4*)h0)[192 + t];
        const float4 bv = *(const float4*)&b2[4 * t];
        float4 o;
        o.x = fmaf(((p0.x + p1.x) + p2.x) + p3.x, 1.0f / KK, bv.x);
        o.y = fmaf(((p0.y + p1.y) + p2.y) + p3.y, 1.0f / KK, bv.y);
        o.z = fmaf(((p0.z + p1.z) + p2.z) + p3.z, 1.0f / KK, bv.z);
        o.w = fmaf(((p0.w + p1.w) + p2.w) + p3.w, 1.0f / KK, bv.w);
        *(float4*)&out[(size_t)bs * HID + 4 * t] = o;
    }
}

extern "C" void kernel_launch(void* const* d_in, const int* in_sizes, int n_in,
                              void* d_out, int out_size, void* d_ws, size_t ws_size,
                              hipStream_t stream) {
    const float* pos  = (const float*)d_in[0];
    const int*   sni  = (const int*)  d_in[1];
    const float* w_in = (const float*)d_in[2];
    const float* b_in = (const float*)d_in[3];
    const float* w1   = (const float*)d_in[4];
    const float* b1   = (const float*)d_in[5];
    const float* w2   = (const float*)d_in[6];
    const float* b2   = (const float*)d_in[7];
    float* out = (float*)d_out;
    (void)d_ws; (void)ws_size; (void)in_sizes; (void)n_in; (void)out_size;

    dim3 grid(BB * SS), block(NTH);
    hipLaunchKernelGGL(snp_kernel, grid, block, 0, stream,
                       pos, sni, w_in, b_in, w1, b1, w2, b2, out);
}